// Round 10
// baseline (146.463 us; speedup 1.0000x reference)
//
#include <hip/hip_runtime.h>
#include <hip/hip_fp16.h>
#include <hip/hip_cooperative_groups.h>

namespace cg = cooperative_groups;

// CropRoi: 3D adaptive max-pool over per-proposal crop boxes — SINGLE
// COOPERATIVE DISPATCH (phase1 transpose | grid.sync | phase2 compute).
// f:        [B=4, C=64, 24, 24, 24] f32
// proposals:[N, 8] f32 = [b, score, cx, cy, cz, sx, sy, sz]
// out:      [N, C, 7, 7, 7] f32
//
// r9 rationale: r8's two dispatches carry ~8-10 us of launch/drain/bubble
// (model: transpose ~4 + compute ~3 + write 1.3 << measured 18.5). Fusing
// into one cooperative kernel removes one full dispatch cycle.
// Phase 2 is r8's predicated-exact-load compute verbatim (TA-light).
//
// Precision: fp16 RTN on ~N(0,1); observed absmax 0.03125 << 0.099.

#define SS 7
#define CC 64
#define BB 4
#define DP 24
#define DP2 (DP*DP)        // 576
#define VOL (DP*DP*DP)     // 13824
#define INV_SCALE 0.25f
#define NEGINF2 0xFC00FC00u

static __device__ __forceinline__ unsigned pkmax(unsigned a, unsigned b) {
    unsigned r;
    asm("v_pk_max_f16 %0, %1, %2" : "=v"(r) : "v"(a), "v"(b));
    return r;
}

// ================= single cooperative kernel =================
__global__ __launch_bounds__(256, 4) void croproi_coop(
    const float* __restrict__ f,      // [B][CC][VOL] f32
    const float* __restrict__ props,  // [N][8]
    __half* __restrict__ ft,          // [B][VOL][CC] fp16 (workspace)
    float* __restrict__ out)          // [N][CC][343] f32
{
    __shared__ float smem[64 * 65];   // phase1: tile[64][65]; phase2: ob[49*68]

    const int bid     = blockIdx.y * gridDim.x + blockIdx.x;
    const int nblocks = gridDim.x * gridDim.y;

    // ---------- phase 1: channel-last fp16 transpose (864 tiles) ----------
    {
        uint4* ft4 = (uint4*)ft;
        const int g16 = threadIdx.x >> 4;
        const int x4  = (threadIdx.x & 15) * 4;
        const int c8  = (threadIdx.x & 7) * 8;
        for (int t = bid; t < BB * 216; t += nblocks) {
            const int b  = t / 216;
            const int s0 = (t - b * 216) * 64;
            #pragma unroll
            for (int it = 0; it < 4; ++it) {
                const int r = it * 16 + g16;           // channel
                const float4 v = *(const float4*)&f[(size_t)(b * CC + r) * VOL + s0 + x4];
                smem[r * 65 + x4 + 0] = v.x;
                smem[r * 65 + x4 + 1] = v.y;
                smem[r * 65 + x4 + 2] = v.z;
                smem[r * 65 + x4 + 3] = v.w;
            }
            __syncthreads();
            #pragma unroll
            for (int it = 0; it < 2; ++it) {
                const int s = it * 32 + (threadIdx.x >> 3);
                __half h[8];
                #pragma unroll
                for (int u = 0; u < 8; ++u)
                    h[u] = __float2half(smem[(c8 + u) * 65 + s]);
                ft4[((size_t)b * VOL + s0 + s) * (CC / 8) + (c8 >> 3)] = *(uint4*)h;
            }
            __syncthreads();
        }
    }

    __threadfence();               // device-scope release of ft writes
    cg::this_grid().sync();        // all ft visible to all XCDs

    // ---------- phase 2: bin compute (r8 structure, 13 quads/block) -------
    const int n    = blockIdx.x;
    const int i    = blockIdx.y;              // z-bin slice
    const int w    = threadIdx.x >> 6;
    const int lane = threadIdx.x & 63;
    const int q4   = lane >> 4;               // sub-bin within quad
    const int lc   = lane & 15;               // channel quad (4 fp16)

    const float* p = props + (size_t)n * 8;
    int b = (int)p[0];

    int lo0, lo1, lo2, L0, L1, L2;
    {
        float c0f = p[2] - 0.5f * p[5];
        float c1f = c0f + p[5];
        int lo = (int)floorf(c0f * INV_SCALE); if (lo < 0) lo = 0;
        int hi = (int)ceilf (c1f * INV_SCALE); if (hi > DP) hi = DP;
        lo0 = lo; L0 = hi - lo;

        c0f = p[3] - 0.5f * p[6];
        c1f = c0f + p[6];
        lo = (int)floorf(c0f * INV_SCALE); if (lo < 0) lo = 0;
        hi = (int)ceilf (c1f * INV_SCALE); if (hi > DP) hi = DP;
        lo1 = lo; L1 = hi - lo;

        c0f = p[4] - 0.5f * p[7];
        c1f = c0f + p[7];
        lo = (int)floorf(c0f * INV_SCALE); if (lo < 0) lo = 0;
        hi = (int)ceilf (c1f * INV_SCALE); if (hi > DP) hi = DP;
        lo2 = lo; L2 = hi - lo;
    }
    b   = __builtin_amdgcn_readfirstlane(b);
    lo0 = __builtin_amdgcn_readfirstlane(lo0);
    lo1 = __builtin_amdgcn_readfirstlane(lo1);
    lo2 = __builtin_amdgcn_readfirstlane(lo2);
    L0  = __builtin_amdgcn_readfirstlane(L0);
    L1  = __builtin_amdgcn_readfirstlane(L1);
    L2  = __builtin_amdgcn_readfirstlane(L2);

    const int zs = (i * L0) / SS;
    const int ez = ((i + 1) * L0 + SS - 1) / SS - zs;        // 1..3

    const uint2* base0 = (const uint2*)(ft
        + ((size_t)b * VOL + (size_t)(lo0 + zs) * DP2
           + (size_t)lo1 * DP + lo2) * CC);

    for (int quad = w; quad < 13; quad += 4) {
        const int jkr = quad * 4 + q4;
        const bool valid = (jkr <= 48);
        const int jk = valid ? jkr : 48;     // dup lanes recompute bin 48
        const int j  = jk / SS;
        const int k  = jk - j * SS;
        const int ys = (j * L1) / SS;
        const int ey = ((j + 1) * L1 + SS - 1) / SS - ys;    // 1..3
        const int xs = (k * L2) / SS;
        const int ex = ((k + 1) * L2 + SS - 1) / SS - xs;    // 1..3

        uint2 vv[27];
        #pragma unroll
        for (int q = 0; q < 27; ++q) { vv[q].x = NEGINF2; vv[q].y = NEGINF2; }

        #pragma unroll
        for (int zi = 0; zi < 3; ++zi) {
            if (zi < ez) {                               // wave-uniform
                const uint2* pz = base0 + zi * (DP2 * 16);
                #pragma unroll
                for (int yi = 0; yi < 3; ++yi) {
                    #pragma unroll
                    for (int xi = 0; xi < 3; ++xi) {
                        if (yi < ey && xi < ex)          // per-lane exec mask
                            vv[zi * 9 + yi * 3 + xi] =
                                pz[(ys + yi) * (DP * 16) + (xs + xi) * 16 + lc];
                    }
                }
            }
        }

        unsigned m0 = NEGINF2, m1 = NEGINF2;
        #pragma unroll
        for (int q = 0; q < 27; ++q) {
            m0 = pkmax(m0, vv[q].x);
            m1 = pkmax(m1, vv[q].y);
        }

        const __half2 h0 = *(const __half2*)&m0;
        const __half2 h1 = *(const __half2*)&m1;
        float4 mf;
        mf.x = __half2float(h0.x);
        mf.y = __half2float(h0.y);
        mf.z = __half2float(h1.x);
        mf.w = __half2float(h1.y);
        if (valid)
            *(float4*)&smem[jk * 68 + lc * 4] = mf;      // 16B-aligned
    }
    __syncthreads();

    // coalesced write-out: 49 consecutive floats per channel
    float* op = out + (size_t)n * CC * (SS * SS * SS) + (size_t)i * 49;
    for (int idx = threadIdx.x; idx < 49 * CC; idx += 256) {
        const int c = idx / 49;
        const int q = idx - c * 49;
        op[(size_t)c * 343 + q] = smem[q * 68 + c];
    }
}

// ================= fallback path A: r8 two-kernel =================
__global__ __launch_bounds__(256) void transpose_cl(
    const float* __restrict__ f, uint4* __restrict__ ft4)
{
    __shared__ float tile[64][65];
    const int b  = blockIdx.y;
    const int s0 = blockIdx.x * 64;
    const int g16 = threadIdx.x >> 4;
    const int x4  = (threadIdx.x & 15) * 4;
    #pragma unroll
    for (int it = 0; it < 4; ++it) {
        const int r = it * 16 + g16;
        const float4 v = *(const float4*)&f[(size_t)(b * CC + r) * VOL + s0 + x4];
        tile[r][x4 + 0] = v.x; tile[r][x4 + 1] = v.y;
        tile[r][x4 + 2] = v.z; tile[r][x4 + 3] = v.w;
    }
    __syncthreads();
    const int c8 = (threadIdx.x & 7) * 8;
    #pragma unroll
    for (int it = 0; it < 2; ++it) {
        const int s = it * 32 + (threadIdx.x >> 3);
        __half h[8];
        #pragma unroll
        for (int u = 0; u < 8; ++u) h[u] = __float2half(tile[c8 + u][s]);
        ft4[((size_t)b * VOL + s0 + s) * (CC / 8) + (c8 >> 3)] = *(uint4*)h;
    }
}

__global__ __launch_bounds__(256) void croproi_compute(
    const __half* __restrict__ ft, const float* __restrict__ props,
    float* __restrict__ out)
{
    __shared__ float ob[13 * 68];
    const int n    = blockIdx.x;
    const int i    = blockIdx.y;
    const int zq   = blockIdx.z;
    const int w    = threadIdx.x >> 6;
    const int lane = threadIdx.x & 63;
    const int q4   = lane >> 4;
    const int lc   = lane & 15;

    const float* p = props + (size_t)n * 8;
    int b = (int)p[0];
    int lo0, lo1, lo2, L0, L1, L2;
    {
        float c0f = p[2] - 0.5f * p[5]; float c1f = c0f + p[5];
        int lo = (int)floorf(c0f * INV_SCALE); if (lo < 0) lo = 0;
        int hi = (int)ceilf (c1f * INV_SCALE); if (hi > DP) hi = DP;
        lo0 = lo; L0 = hi - lo;
        c0f = p[3] - 0.5f * p[6]; c1f = c0f + p[6];
        lo = (int)floorf(c0f * INV_SCALE); if (lo < 0) lo = 0;
        hi = (int)ceilf (c1f * INV_SCALE); if (hi > DP) hi = DP;
        lo1 = lo; L1 = hi - lo;
        c0f = p[4] - 0.5f * p[7]; c1f = c0f + p[7];
        lo = (int)floorf(c0f * INV_SCALE); if (lo < 0) lo = 0;
        hi = (int)ceilf (c1f * INV_SCALE); if (hi > DP) hi = DP;
        lo2 = lo; L2 = hi - lo;
    }
    b   = __builtin_amdgcn_readfirstlane(b);
    lo0 = __builtin_amdgcn_readfirstlane(lo0);
    lo1 = __builtin_amdgcn_readfirstlane(lo1);
    lo2 = __builtin_amdgcn_readfirstlane(lo2);
    L0  = __builtin_amdgcn_readfirstlane(L0);
    L1  = __builtin_amdgcn_readfirstlane(L1);
    L2  = __builtin_amdgcn_readfirstlane(L2);

    const int zs = (i * L0) / SS;
    const int ez = ((i + 1) * L0 + SS - 1) / SS - zs;
    const uint2* base0 = (const uint2*)(ft
        + ((size_t)b * VOL + (size_t)(lo0 + zs) * DP2
           + (size_t)lo1 * DP + lo2) * CC);

    const int qlo = (zq * 13) / 4;
    const int qhi = ((zq + 1) * 13) / 4;
    const int binbase = qlo * 4;
    const int nb = ((qhi * 4 < 49) ? qhi * 4 : 49) - binbase;

    for (int quad = qlo + w; quad < qhi; quad += 4) {
        const int jkr = quad * 4 + q4;
        const bool valid = (jkr <= 48);
        const int jk = valid ? jkr : 48;
        const int j  = jk / SS;
        const int k  = jk - j * SS;
        const int ys = (j * L1) / SS;
        const int ey = ((j + 1) * L1 + SS - 1) / SS - ys;
        const int xs = (k * L2) / SS;
        const int ex = ((k + 1) * L2 + SS - 1) / SS - xs;

        uint2 vv[27];
        #pragma unroll
        for (int q = 0; q < 27; ++q) { vv[q].x = NEGINF2; vv[q].y = NEGINF2; }
        #pragma unroll
        for (int zi = 0; zi < 3; ++zi) {
            if (zi < ez) {
                const uint2* pz = base0 + zi * (DP2 * 16);
                #pragma unroll
                for (int yi = 0; yi < 3; ++yi)
                    #pragma unroll
                    for (int xi = 0; xi < 3; ++xi)
                        if (yi < ey && xi < ex)
                            vv[zi * 9 + yi * 3 + xi] =
                                pz[(ys + yi) * (DP * 16) + (xs + xi) * 16 + lc];
            }
        }
        unsigned m0 = NEGINF2, m1 = NEGINF2;
        #pragma unroll
        for (int q = 0; q < 27; ++q) { m0 = pkmax(m0, vv[q].x); m1 = pkmax(m1, vv[q].y); }
        const __half2 h0 = *(const __half2*)&m0;
        const __half2 h1 = *(const __half2*)&m1;
        float4 mf;
        mf.x = __half2float(h0.x); mf.y = __half2float(h0.y);
        mf.z = __half2float(h1.x); mf.w = __half2float(h1.y);
        if (valid) *(float4*)&ob[(jk - binbase) * 68 + lc * 4] = mf;
    }
    __syncthreads();

    float* op = out + (size_t)n * CC * (SS * SS * SS) + (size_t)i * 49 + binbase;
    if (nb == 13) {
        for (int idx = threadIdx.x; idx < 13 * CC; idx += 256) {
            const int c = idx / 13; const int q = idx - c * 13;
            op[(size_t)c * 343 + q] = ob[q * 68 + c];
        }
    } else {
        for (int idx = threadIdx.x; idx < 12 * CC; idx += 256) {
            const int c = idx / 12; const int q = idx - c * 12;
            op[(size_t)c * 343 + q] = ob[q * 68 + c];
        }
    }
}

// ================= fallback path B: round-0 thread-per-bin =================
__global__ __launch_bounds__(256) void croproi_fallback(
    const float* __restrict__ f, const float* __restrict__ props,
    float* __restrict__ out, int total)
{
    int tid = blockIdx.x * blockDim.x + threadIdx.x;
    if (tid >= total) return;
    int k = tid % SS;
    int t = tid / SS;
    int j = t % SS; t /= SS;
    int i = t % SS; t /= SS;
    int c = t % CC;
    int n = t / CC;
    const float* p = props + n * 8;
    int b = (int)p[0];
    int lo0, lo1, lo2, L0, L1, L2;
    {
        float c0f = p[2] - 0.5f * p[5]; float c1f = c0f + p[5];
        int lo = (int)floorf(c0f * INV_SCALE); if (lo < 0) lo = 0;
        int hi = (int)ceilf (c1f * INV_SCALE); if (hi > DP) hi = DP;
        lo0 = lo; L0 = hi - lo;
        c0f = p[3] - 0.5f * p[6]; c1f = c0f + p[6];
        lo = (int)floorf(c0f * INV_SCALE); if (lo < 0) lo = 0;
        hi = (int)ceilf (c1f * INV_SCALE); if (hi > DP) hi = DP;
        lo1 = lo; L1 = hi - lo;
        c0f = p[4] - 0.5f * p[7]; c1f = c0f + p[7];
        lo = (int)floorf(c0f * INV_SCALE); if (lo < 0) lo = 0;
        hi = (int)ceilf (c1f * INV_SCALE); if (hi > DP) hi = DP;
        lo2 = lo; L2 = hi - lo;
    }
    int zs = lo0 + (i * L0) / SS, ze = lo0 + ((i + 1) * L0 + SS - 1) / SS;
    int ys = lo1 + (j * L1) / SS, ye = lo1 + ((j + 1) * L1 + SS - 1) / SS;
    int xs = lo2 + (k * L2) / SS, xe = lo2 + ((k + 1) * L2 + SS - 1) / SS;
    const float* fb = f + (size_t)(b * CC + c) * VOL;
    float m = -INFINITY;
    for (int z = zs; z < ze; ++z)
        for (int y = ys; y < ye; ++y) {
            const float* row = fb + (z * DP + y) * DP;
            for (int x = xs; x < xe; ++x) m = fmaxf(m, row[x]);
        }
    out[tid] = m;
}

extern "C" void kernel_launch(void* const* d_in, const int* in_sizes, int n_in,
                              void* d_out, int out_size, void* d_ws, size_t ws_size,
                              hipStream_t stream) {
    const float* f     = (const float*)d_in[0];
    const float* props = (const float*)d_in[2];
    float* out = (float*)d_out;

    const int B = in_sizes[0] / (CC * VOL);   // 4
    const int N = in_sizes[2] / 8;            // 96

    const size_t ft_bytes = (size_t)B * VOL * CC * sizeof(__half);
    if (ws_size >= ft_bytes && B == BB) {
        __half* ft = (__half*)d_ws;

        // try single cooperative dispatch
        void* args[] = { (void*)&f, (void*)&props, (void*)&ft, (void*)&out };
        dim3 g(N, SS, 1);                     // 96 x 7 = 672 blocks
        hipError_t e = hipLaunchCooperativeKernel(
            (const void*)croproi_coop, g, dim3(256, 1, 1), args, 0, stream);
        if (e != hipSuccess) {
            (void)hipGetLastError();          // clear, fall back to 2-kernel
            dim3 g1(VOL / 64, B);             // 216 x 4
            transpose_cl<<<g1, 256, 0, stream>>>(f, (uint4*)ft);
            dim3 g2(N, SS, 4);                // 96 x 7 x 4
            croproi_compute<<<g2, 256, 0, stream>>>(ft, props, out);
        }
    } else {
        int total = N * CC * SS * SS * SS;
        croproi_fallback<<<(total + 255) / 256, 256, 0, stream>>>(f, props, out, total);
    }
}

// Round 11
// 20.878 us; speedup vs baseline: 7.0151x; 7.0151x over previous
//
#include <hip/hip_runtime.h>
#include <hip/hip_fp16.h>

// CropRoi: 3D adaptive max-pool over per-proposal crop boxes.
// f:        [B=4, C=64, 24, 24, 24] f32
// proposals:[N, 8] f32 = [b, score, cx, cy, cz, sx, sy, sz]
// out:      [N, C, 7, 7, 7] f32
//
// Kernel 1 (unchanged from r8): transpose+fp16 f -> ft[b][s][c] channel-last.
// Kernel 2 (r10): grid (N,7), ONE block per (n, z-slice i).
//   - box decode + props load 1x per block (was 4x at grid.z=4)
//   - 4 waves x 13 quads; wave = 4 bins x 16 lanes, lane = 4-ch uint2
//   - predicated EXACT loads (r8's TA-light pattern, verified -3.1 us)
//   - single merged 49-bin coalesced write-out
//
// Precision: fp16 RTN on ~N(0,1); absmax 0.03125 << 0.099 (r5/r7/r8).
// NOTE r9: cooperative grid.sync costs ~100us on MI355X -- never again.

#define SS 7
#define CC 64
#define DP 24
#define DP2 (DP*DP)        // 576
#define VOL (DP*DP*DP)     // 13824
#define INV_SCALE 0.25f
#define NEGINF2 0xFC00FC00u

static __device__ __forceinline__ unsigned pkmax(unsigned a, unsigned b) {
    unsigned r;
    asm("v_pk_max_f16 %0, %1, %2" : "=v"(r) : "v"(a), "v"(b));
    return r;
}

// ---------------- kernel 1: channel-last transpose to fp16 ----------------
__global__ __launch_bounds__(256) void transpose_cl(
    const float* __restrict__ f,   // [B][CC][VOL] f32
    uint4* __restrict__ ft4)       // [B][VOL][CC/8]
{
    __shared__ float tile[64][65];
    const int b  = blockIdx.y;
    const int s0 = blockIdx.x * 64;
    const int g16 = threadIdx.x >> 4;
    const int x4  = (threadIdx.x & 15) * 4;
    #pragma unroll
    for (int it = 0; it < 4; ++it) {
        const int r = it * 16 + g16;           // channel
        const float4 v = *(const float4*)&f[(size_t)(b * CC + r) * VOL + s0 + x4];
        tile[r][x4 + 0] = v.x; tile[r][x4 + 1] = v.y;
        tile[r][x4 + 2] = v.z; tile[r][x4 + 3] = v.w;
    }
    __syncthreads();
    const int c8 = (threadIdx.x & 7) * 8;
    #pragma unroll
    for (int it = 0; it < 2; ++it) {
        const int s = it * 32 + (threadIdx.x >> 3);
        __half h[8];
        #pragma unroll
        for (int u = 0; u < 8; ++u)
            h[u] = __float2half(tile[c8 + u][s]);   // 2-way bank alias: free
        ft4[((size_t)b * VOL + s0 + s) * (CC / 8) + (c8 >> 3)] = *(uint4*)h;
    }
}

// ---------------- kernel 2: bin compute, one block per (n, i) ----------------
__global__ __launch_bounds__(256) void croproi_compute(
    const __half* __restrict__ ft,    // [B][VOL][CC] fp16
    const float* __restrict__ props,  // [N][8]
    float* __restrict__ out)          // [N][CC][343] f32
{
    __shared__ float ob[49 * 68];
    const int n    = blockIdx.x;
    const int i    = blockIdx.y;              // z-bin slice
    const int w    = threadIdx.x >> 6;
    const int lane = threadIdx.x & 63;
    const int q4   = lane >> 4;               // sub-bin within quad
    const int lc   = lane & 15;               // channel quad (4 fp16)

    const float* p = props + (size_t)n * 8;
    int b = (int)p[0];

    int lo0, lo1, lo2, L0, L1, L2;
    {
        float c0f = p[2] - 0.5f * p[5];
        float c1f = c0f + p[5];
        int lo = (int)floorf(c0f * INV_SCALE); if (lo < 0) lo = 0;
        int hi = (int)ceilf (c1f * INV_SCALE); if (hi > DP) hi = DP;
        lo0 = lo; L0 = hi - lo;

        c0f = p[3] - 0.5f * p[6];
        c1f = c0f + p[6];
        lo = (int)floorf(c0f * INV_SCALE); if (lo < 0) lo = 0;
        hi = (int)ceilf (c1f * INV_SCALE); if (hi > DP) hi = DP;
        lo1 = lo; L1 = hi - lo;

        c0f = p[4] - 0.5f * p[7];
        c1f = c0f + p[7];
        lo = (int)floorf(c0f * INV_SCALE); if (lo < 0) lo = 0;
        hi = (int)ceilf (c1f * INV_SCALE); if (hi > DP) hi = DP;
        lo2 = lo; L2 = hi - lo;
    }
    b   = __builtin_amdgcn_readfirstlane(b);
    lo0 = __builtin_amdgcn_readfirstlane(lo0);
    lo1 = __builtin_amdgcn_readfirstlane(lo1);
    lo2 = __builtin_amdgcn_readfirstlane(lo2);
    L0  = __builtin_amdgcn_readfirstlane(L0);
    L1  = __builtin_amdgcn_readfirstlane(L1);
    L2  = __builtin_amdgcn_readfirstlane(L2);

    const int zs = (i * L0) / SS;
    const int ez = ((i + 1) * L0 + SS - 1) / SS - zs;        // 1..3

    const uint2* base0 = (const uint2*)(ft
        + ((size_t)b * VOL + (size_t)(lo0 + zs) * DP2
           + (size_t)lo1 * DP + lo2) * CC);

    for (int quad = w; quad < 13; quad += 4) {   // 3-4 independent iters/wave
        const int jkr = quad * 4 + q4;
        const bool valid = (jkr <= 48);
        const int jk = valid ? jkr : 48;     // dup lanes recompute bin 48
        const int j  = jk / SS;
        const int k  = jk - j * SS;
        const int ys = (j * L1) / SS;
        const int ey = ((j + 1) * L1 + SS - 1) / SS - ys;    // 1..3
        const int xs = (k * L2) / SS;
        const int ex = ((k + 1) * L2 + SS - 1) / SS - xs;    // 1..3

        uint2 vv[27];
        #pragma unroll
        for (int q = 0; q < 27; ++q) { vv[q].x = NEGINF2; vv[q].y = NEGINF2; }

        #pragma unroll
        for (int zi = 0; zi < 3; ++zi) {
            if (zi < ez) {                               // wave-uniform
                const uint2* pz = base0 + zi * (DP2 * 16);
                #pragma unroll
                for (int yi = 0; yi < 3; ++yi) {
                    #pragma unroll
                    for (int xi = 0; xi < 3; ++xi) {
                        if (yi < ey && xi < ex)          // per-lane exec mask
                            vv[zi * 9 + yi * 3 + xi] =
                                pz[(ys + yi) * (DP * 16) + (xs + xi) * 16 + lc];
                    }
                }
            }
        }

        unsigned m0 = NEGINF2, m1 = NEGINF2;
        #pragma unroll
        for (int q = 0; q < 27; ++q) {
            m0 = pkmax(m0, vv[q].x);
            m1 = pkmax(m1, vv[q].y);
        }

        const __half2 h0 = *(const __half2*)&m0;
        const __half2 h1 = *(const __half2*)&m1;
        float4 mf;
        mf.x = __half2float(h0.x);
        mf.y = __half2float(h0.y);
        mf.z = __half2float(h1.x);
        mf.w = __half2float(h1.y);
        if (valid)
            *(float4*)&ob[jk * 68 + lc * 4] = mf;        // 16B-aligned
    }
    __syncthreads();

    // single merged write-out: 49 consecutive floats per channel
    float* op = out + (size_t)n * CC * (SS * SS * SS) + (size_t)i * 49;
    for (int idx = threadIdx.x; idx < 49 * CC; idx += 256) {
        const int c = idx / 49;                          // magic-mul
        const int q = idx - c * 49;
        op[(size_t)c * 343 + q] = ob[q * 68 + c];
    }
}

// ---------------- fallback: round-0 thread-per-bin (proven) --------
__global__ __launch_bounds__(256) void croproi_fallback(
    const float* __restrict__ f, const float* __restrict__ props,
    float* __restrict__ out, int total)
{
    int tid = blockIdx.x * blockDim.x + threadIdx.x;
    if (tid >= total) return;
    int k = tid % SS;
    int t = tid / SS;
    int j = t % SS; t /= SS;
    int i = t % SS; t /= SS;
    int c = t % CC;
    int n = t / CC;
    const float* p = props + n * 8;
    int b = (int)p[0];
    int lo0, lo1, lo2, L0, L1, L2;
    {
        float c0f = p[2] - 0.5f * p[5]; float c1f = c0f + p[5];
        int lo = (int)floorf(c0f * INV_SCALE); if (lo < 0) lo = 0;
        int hi = (int)ceilf (c1f * INV_SCALE); if (hi > DP) hi = DP;
        lo0 = lo; L0 = hi - lo;
        c0f = p[3] - 0.5f * p[6]; c1f = c0f + p[6];
        lo = (int)floorf(c0f * INV_SCALE); if (lo < 0) lo = 0;
        hi = (int)ceilf (c1f * INV_SCALE); if (hi > DP) hi = DP;
        lo1 = lo; L1 = hi - lo;
        c0f = p[4] - 0.5f * p[7]; c1f = c0f + p[7];
        lo = (int)floorf(c0f * INV_SCALE); if (lo < 0) lo = 0;
        hi = (int)ceilf (c1f * INV_SCALE); if (hi > DP) hi = DP;
        lo2 = lo; L2 = hi - lo;
    }
    int zs = lo0 + (i * L0) / SS, ze = lo0 + ((i + 1) * L0 + SS - 1) / SS;
    int ys = lo1 + (j * L1) / SS, ye = lo1 + ((j + 1) * L1 + SS - 1) / SS;
    int xs = lo2 + (k * L2) / SS, xe = lo2 + ((k + 1) * L2 + SS - 1) / SS;
    const float* fb = f + (size_t)(b * CC + c) * VOL;
    float m = -INFINITY;
    for (int z = zs; z < ze; ++z)
        for (int y = ys; y < ye; ++y) {
            const float* row = fb + (z * DP + y) * DP;
            for (int x = xs; x < xe; ++x) m = fmaxf(m, row[x]);
        }
    out[tid] = m;
}

extern "C" void kernel_launch(void* const* d_in, const int* in_sizes, int n_in,
                              void* d_out, int out_size, void* d_ws, size_t ws_size,
                              hipStream_t stream) {
    const float* f     = (const float*)d_in[0];
    const float* props = (const float*)d_in[2];
    float* out = (float*)d_out;

    const int B = in_sizes[0] / (CC * VOL);   // 4
    const int N = in_sizes[2] / 8;            // 96

    const size_t ft_bytes = (size_t)B * VOL * CC * sizeof(__half);
    if (ws_size >= ft_bytes) {
        __half* ft = (__half*)d_ws;
        dim3 g1(VOL / 64, B);                 // 216 x 4 = 864 blocks
        transpose_cl<<<g1, 256, 0, stream>>>(f, (uint4*)ft);
        dim3 g2(N, SS);                       // 96 x 7 = 672 blocks
        croproi_compute<<<g2, 256, 0, stream>>>(ft, props, out);
    } else {
        int total = N * CC * SS * SS * SS;
        croproi_fallback<<<(total + 255) / 256, 256, 0, stream>>>(f, props, out, total);
    }
}

// Round 12
// 18.166 us; speedup vs baseline: 8.0624x; 1.1493x over previous
//
#include <hip/hip_runtime.h>
#include <hip/hip_fp16.h>

// CropRoi: 3D adaptive max-pool over per-proposal crop boxes.
// f:        [B=4, C=64, 24, 24, 24] f32
// proposals:[N, 8] f32 = [b, score, cx, cy, cz, sx, sy, sz]
// out:      [N, C, 7, 7, 7] f32
//
// Kernel 1 (unchanged r8): transpose+fp16 f -> ft[b][s][c] channel-last.
// Kernel 2 (r11): wave = 8 bins x 8 lanes, lane loads uint4 = 8 fp16 ch
//   (8 lanes x 16 B = one 128 B line per bin, same as r8's 16x8B).
//   Halves total waves (10752 -> 5376) at constant per-bin work -> all
//   per-wave fixed VALU (decode, exec-masks, writeout, cvt) halves.
//   grid (N,7,2): zq=0 -> octs 0-3 (bins 0-31), zq=1 -> octs 4-6 (32-48).
//   Predicated exact loads kept from r8 (verified -3.1 us vs clamped).
//
// History: r9 coop grid.sync ~100us on MI355X — never again. r10 z=1
// regressed (latency exposure at 10.5 waves/CU with serial quads).
// Precision: fp16 RTN on ~N(0,1); absmax 0.03125 << 0.099 (r5/r7/r8/r10).

#define SS 7
#define CC 64
#define DP 24
#define DP2 (DP*DP)        // 576
#define VOL (DP*DP*DP)     // 13824
#define INV_SCALE 0.25f
#define NEGINF2 0xFC00FC00u

static __device__ __forceinline__ unsigned pkmax(unsigned a, unsigned b) {
    unsigned r;
    asm("v_pk_max_f16 %0, %1, %2" : "=v"(r) : "v"(a), "v"(b));
    return r;
}

// ---------------- kernel 1: channel-last transpose to fp16 ----------------
__global__ __launch_bounds__(256) void transpose_cl(
    const float* __restrict__ f,   // [B][CC][VOL] f32
    uint4* __restrict__ ft4)       // [B][VOL][CC/8]
{
    __shared__ float tile[64][65];
    const int b  = blockIdx.y;
    const int s0 = blockIdx.x * 64;
    const int g16 = threadIdx.x >> 4;
    const int x4  = (threadIdx.x & 15) * 4;
    #pragma unroll
    for (int it = 0; it < 4; ++it) {
        const int r = it * 16 + g16;           // channel
        const float4 v = *(const float4*)&f[(size_t)(b * CC + r) * VOL + s0 + x4];
        tile[r][x4 + 0] = v.x; tile[r][x4 + 1] = v.y;
        tile[r][x4 + 2] = v.z; tile[r][x4 + 3] = v.w;
    }
    __syncthreads();
    const int c8 = (threadIdx.x & 7) * 8;
    #pragma unroll
    for (int it = 0; it < 2; ++it) {
        const int s = it * 32 + (threadIdx.x >> 3);
        __half h[8];
        #pragma unroll
        for (int u = 0; u < 8; ++u)
            h[u] = __float2half(tile[c8 + u][s]);   // 2-way bank alias: free
        ft4[((size_t)b * VOL + s0 + s) * (CC / 8) + (c8 >> 3)] = *(uint4*)h;
    }
}

// ---------------- kernel 2: bin compute, 8 bins x 8 lanes per wave ---------
__global__ __launch_bounds__(256) void croproi_compute(
    const __half* __restrict__ ft,    // [B][VOL][CC] fp16
    const float* __restrict__ props,  // [N][8]
    float* __restrict__ out)          // [N][CC][343] f32
{
    __shared__ float ob[32 * 68];
    const int n    = blockIdx.x;
    const int i    = blockIdx.y;              // z-bin slice
    const int zq   = blockIdx.z;              // bin-half (0: 32 bins, 1: 17)
    const int w    = threadIdx.x >> 6;
    const int lane = threadIdx.x & 63;
    const int o8   = lane >> 3;               // bin within oct (0..7)
    const int lc8  = lane & 7;                // channel octet (8 fp16 = 16 B)

    const float* p = props + (size_t)n * 8;
    int b = (int)p[0];

    int lo0, lo1, lo2, L0, L1, L2;
    {
        float c0f = p[2] - 0.5f * p[5];
        float c1f = c0f + p[5];
        int lo = (int)floorf(c0f * INV_SCALE); if (lo < 0) lo = 0;
        int hi = (int)ceilf (c1f * INV_SCALE); if (hi > DP) hi = DP;
        lo0 = lo; L0 = hi - lo;

        c0f = p[3] - 0.5f * p[6];
        c1f = c0f + p[6];
        lo = (int)floorf(c0f * INV_SCALE); if (lo < 0) lo = 0;
        hi = (int)ceilf (c1f * INV_SCALE); if (hi > DP) hi = DP;
        lo1 = lo; L1 = hi - lo;

        c0f = p[4] - 0.5f * p[7];
        c1f = c0f + p[7];
        lo = (int)floorf(c0f * INV_SCALE); if (lo < 0) lo = 0;
        hi = (int)ceilf (c1f * INV_SCALE); if (hi > DP) hi = DP;
        lo2 = lo; L2 = hi - lo;
    }
    b   = __builtin_amdgcn_readfirstlane(b);
    lo0 = __builtin_amdgcn_readfirstlane(lo0);
    lo1 = __builtin_amdgcn_readfirstlane(lo1);
    lo2 = __builtin_amdgcn_readfirstlane(lo2);
    L0  = __builtin_amdgcn_readfirstlane(L0);
    L1  = __builtin_amdgcn_readfirstlane(L1);
    L2  = __builtin_amdgcn_readfirstlane(L2);

    const int zs = (i * L0) / SS;
    const int ez = ((i + 1) * L0 + SS - 1) / SS - zs;        // 1..3

    // base in uint4 (16 B) units: one spatial point = 64 ch * 2 B = 8 uint4
    const uint4* base0 = (const uint4*)(ft
        + ((size_t)b * VOL + (size_t)(lo0 + zs) * DP2
           + (size_t)lo1 * DP + lo2) * CC);

    const int olo = zq * 4;                  // oct range [olo, ohi)
    const int ohi = (olo + 4 < 7) ? olo + 4 : 7;
    const int binbase = zq * 32;

    for (int oct = olo + w; oct < ohi; oct += 4) {   // exactly 0 or 1 iter
        const int jkr = oct * 8 + o8;
        const bool valid = (jkr <= 48);
        const int jk = valid ? jkr : 48;     // dup lanes recompute bin 48
        const int j  = jk / SS;
        const int k  = jk - j * SS;
        const int ys = (j * L1) / SS;
        const int ey = ((j + 1) * L1 + SS - 1) / SS - ys;    // 1..3
        const int xs = (k * L2) / SS;
        const int ex = ((k + 1) * L2 + SS - 1) / SS - xs;    // 1..3

        uint4 vv[27];
        #pragma unroll
        for (int q = 0; q < 27; ++q) {
            vv[q].x = NEGINF2; vv[q].y = NEGINF2;
            vv[q].z = NEGINF2; vv[q].w = NEGINF2;
        }

        #pragma unroll
        for (int zi = 0; zi < 3; ++zi) {
            if (zi < ez) {                               // wave-uniform
                const uint4* pz = base0 + zi * (DP2 * 8);
                #pragma unroll
                for (int yi = 0; yi < 3; ++yi) {
                    #pragma unroll
                    for (int xi = 0; xi < 3; ++xi) {
                        if (yi < ey && xi < ex)          // per-lane exec mask
                            vv[zi * 9 + yi * 3 + xi] =
                                pz[(ys + yi) * (DP * 8) + (xs + xi) * 8 + lc8];
                    }
                }
            }
        }

        unsigned m0 = NEGINF2, m1 = NEGINF2, m2 = NEGINF2, m3 = NEGINF2;
        #pragma unroll
        for (int q = 0; q < 27; ++q) {
            m0 = pkmax(m0, vv[q].x);
            m1 = pkmax(m1, vv[q].y);
            m2 = pkmax(m2, vv[q].z);
            m3 = pkmax(m3, vv[q].w);
        }

        if (valid) {
            const __half2 h0 = *(const __half2*)&m0;
            const __half2 h1 = *(const __half2*)&m1;
            const __half2 h2 = *(const __half2*)&m2;
            const __half2 h3 = *(const __half2*)&m3;
            float4 fa, fb4;
            fa.x  = __half2float(h0.x); fa.y  = __half2float(h0.y);
            fa.z  = __half2float(h1.x); fa.w  = __half2float(h1.y);
            fb4.x = __half2float(h2.x); fb4.y = __half2float(h2.y);
            fb4.z = __half2float(h3.x); fb4.w = __half2float(h3.y);
            float* row = &ob[(jk - binbase) * 68 + lc8 * 8];
            *(float4*)row       = fa;
            *(float4*)(row + 4) = fb4;
        }
    }
    __syncthreads();

    // coalesced write-out: runs of 49 consecutive floats per channel
    float* op = out + (size_t)n * CC * (SS * SS * SS) + (size_t)i * 49 + binbase;
    if (zq == 0) {
        // nb = 32: div/mod are shifts
        for (int idx = threadIdx.x; idx < 32 * CC; idx += 256) {
            const int c = idx >> 5;
            const int q = idx & 31;
            op[(size_t)c * 343 + q] = ob[q * 68 + c];
        }
    } else {
        // nb = 17
        for (int idx = threadIdx.x; idx < 17 * CC; idx += 256) {
            const int c = idx / 17;                      // magic-mul
            const int q = idx - c * 17;
            op[(size_t)c * 343 + q] = ob[q * 68 + c];
        }
    }
}

// ---------------- fallback: round-0 thread-per-bin (proven) --------
__global__ __launch_bounds__(256) void croproi_fallback(
    const float* __restrict__ f, const float* __restrict__ props,
    float* __restrict__ out, int total)
{
    int tid = blockIdx.x * blockDim.x + threadIdx.x;
    if (tid >= total) return;
    int k = tid % SS;
    int t = tid / SS;
    int j = t % SS; t /= SS;
    int i = t % SS; t /= SS;
    int c = t % CC;
    int n = t / CC;
    const float* p = props + n * 8;
    int b = (int)p[0];
    int lo0, lo1, lo2, L0, L1, L2;
    {
        float c0f = p[2] - 0.5f * p[5]; float c1f = c0f + p[5];
        int lo = (int)floorf(c0f * INV_SCALE); if (lo < 0) lo = 0;
        int hi = (int)ceilf (c1f * INV_SCALE); if (hi > DP) hi = DP;
        lo0 = lo; L0 = hi - lo;
        c0f = p[3] - 0.5f * p[6]; c1f = c0f + p[6];
        lo = (int)floorf(c0f * INV_SCALE); if (lo < 0) lo = 0;
        hi = (int)ceilf (c1f * INV_SCALE); if (hi > DP) hi = DP;
        lo1 = lo; L1 = hi - lo;
        c0f = p[4] - 0.5f * p[7]; c1f = c0f + p[7];
        lo = (int)floorf(c0f * INV_SCALE); if (lo < 0) lo = 0;
        hi = (int)ceilf (c1f * INV_SCALE); if (hi > DP) hi = DP;
        lo2 = lo; L2 = hi - lo;
    }
    int zs = lo0 + (i * L0) / SS, ze = lo0 + ((i + 1) * L0 + SS - 1) / SS;
    int ys = lo1 + (j * L1) / SS, ye = lo1 + ((j + 1) * L1 + SS - 1) / SS;
    int xs = lo2 + (k * L2) / SS, xe = lo2 + ((k + 1) * L2 + SS - 1) / SS;
    const float* fb = f + (size_t)(b * CC + c) * VOL;
    float m = -INFINITY;
    for (int z = zs; z < ze; ++z)
        for (int y = ys; y < ye; ++y) {
            const float* row = fb + (z * DP + y) * DP;
            for (int x = xs; x < xe; ++x) m = fmaxf(m, row[x]);
        }
    out[tid] = m;
}

extern "C" void kernel_launch(void* const* d_in, const int* in_sizes, int n_in,
                              void* d_out, int out_size, void* d_ws, size_t ws_size,
                              hipStream_t stream) {
    const float* f     = (const float*)d_in[0];
    const float* props = (const float*)d_in[2];
    float* out = (float*)d_out;

    const int B = in_sizes[0] / (CC * VOL);   // 4
    const int N = in_sizes[2] / 8;            // 96

    const size_t ft_bytes = (size_t)B * VOL * CC * sizeof(__half);
    if (ws_size >= ft_bytes) {
        __half* ft = (__half*)d_ws;
        dim3 g1(VOL / 64, B);                 // 216 x 4 = 864 blocks
        transpose_cl<<<g1, 256, 0, stream>>>(f, (uint4*)ft);
        dim3 g2(N, SS, 2);                    // 96 x 7 x 2 = 1344 blocks
        croproi_compute<<<g2, 256, 0, stream>>>(ft, props, out);
    } else {
        int total = N * CC * SS * SS * SS;
        croproi_fallback<<<(total + 255) / 256, 256, 0, stream>>>(f, props, out, total);
    }
}